// Round 1
// baseline (245.381 us; speedup 1.0000x reference)
//
#include <hip/hip_runtime.h>
#include <math.h>

#define V_ 3
#define B_ 2
#define C_ 32
#define D_ 32
#define H_ 128
#define W_ 160
#define HW_ (H_*W_)
#define NPIX_ (B_*H_*W_)              // 40960
#define NCOST_ (B_*D_*H_*W_)          // 1310720
#define NFEATT_ (V_*B_*H_*W_*C_)      // 3932160

// ---------------- 4x4 double inverse (adjugate) ----------------
__device__ __forceinline__ void inv4(const double* m, double* o) {
    double inv[16];
    inv[0]  =  m[5]*m[10]*m[15] - m[5]*m[11]*m[14] - m[9]*m[6]*m[15] + m[9]*m[7]*m[14] + m[13]*m[6]*m[11] - m[13]*m[7]*m[10];
    inv[4]  = -m[4]*m[10]*m[15] + m[4]*m[11]*m[14] + m[8]*m[6]*m[15] - m[8]*m[7]*m[14] - m[12]*m[6]*m[11] + m[12]*m[7]*m[10];
    inv[8]  =  m[4]*m[9]*m[15]  - m[4]*m[11]*m[13] - m[8]*m[5]*m[15] + m[8]*m[7]*m[13] + m[12]*m[5]*m[11] - m[12]*m[7]*m[9];
    inv[12] = -m[4]*m[9]*m[14]  + m[4]*m[10]*m[13] + m[8]*m[5]*m[14] - m[8]*m[6]*m[13] - m[12]*m[5]*m[10] + m[12]*m[6]*m[9];
    inv[1]  = -m[1]*m[10]*m[15] + m[1]*m[11]*m[14] + m[9]*m[2]*m[15] - m[9]*m[3]*m[14] - m[13]*m[2]*m[11] + m[13]*m[3]*m[10];
    inv[5]  =  m[0]*m[10]*m[15] - m[0]*m[11]*m[14] - m[8]*m[2]*m[15] + m[8]*m[3]*m[14] + m[12]*m[2]*m[11] - m[12]*m[3]*m[10];
    inv[9]  = -m[0]*m[9]*m[15]  + m[0]*m[11]*m[13] + m[8]*m[1]*m[15] - m[8]*m[3]*m[13] - m[12]*m[1]*m[11] + m[12]*m[3]*m[9];
    inv[13] =  m[0]*m[9]*m[14]  - m[0]*m[10]*m[13] - m[8]*m[1]*m[14] + m[8]*m[2]*m[13] + m[12]*m[1]*m[10] - m[12]*m[2]*m[9];
    inv[2]  =  m[1]*m[6]*m[15]  - m[1]*m[7]*m[14]  - m[5]*m[2]*m[15] + m[5]*m[3]*m[14] + m[13]*m[2]*m[7]  - m[13]*m[3]*m[6];
    inv[6]  = -m[0]*m[6]*m[15]  + m[0]*m[7]*m[14]  + m[4]*m[2]*m[15] - m[4]*m[3]*m[14] - m[12]*m[2]*m[7]  + m[12]*m[3]*m[6];
    inv[10] =  m[0]*m[5]*m[15]  - m[0]*m[7]*m[13]  - m[4]*m[1]*m[15] + m[4]*m[3]*m[13] + m[12]*m[1]*m[7]  - m[12]*m[3]*m[5];
    inv[14] = -m[0]*m[5]*m[14]  + m[0]*m[6]*m[13]  + m[4]*m[1]*m[14] - m[4]*m[2]*m[13] - m[12]*m[1]*m[6]  + m[12]*m[2]*m[5];
    inv[3]  = -m[1]*m[6]*m[11]  + m[1]*m[7]*m[10]  + m[5]*m[2]*m[11] - m[5]*m[3]*m[10] - m[9]*m[2]*m[7]   + m[9]*m[3]*m[6];
    inv[7]  =  m[0]*m[6]*m[11]  - m[0]*m[7]*m[10]  - m[4]*m[2]*m[11] + m[4]*m[3]*m[10] + m[8]*m[2]*m[7]   - m[8]*m[3]*m[6];
    inv[11] = -m[0]*m[5]*m[11]  + m[0]*m[7]*m[9]   + m[4]*m[1]*m[11] - m[4]*m[3]*m[9]  - m[8]*m[1]*m[7]   + m[8]*m[3]*m[5];
    inv[15] =  m[0]*m[5]*m[10]  - m[0]*m[6]*m[9]   - m[4]*m[1]*m[10] + m[4]*m[2]*m[9]  + m[8]*m[1]*m[6]   - m[8]*m[2]*m[5];
    double det = m[0]*inv[0] + m[1]*inv[4] + m[2]*inv[8] + m[3]*inv[12];
    det = 1.0 / det;
    for (int i = 0; i < 16; i++) o[i] = inv[i] * det;
}

__device__ __forceinline__ void mm4(const double* A, const double* Bm, double* Cm) {
    for (int r = 0; r < 4; r++)
        for (int c = 0; c < 4; c++) {
            double s = 0.0;
            for (int k = 0; k < 4; k++) s += A[r*4+k] * Bm[k*4+c];
            Cm[r*4+c] = s;
        }
}

// proj_out: (V-1, B, 12) = rot[9] + trans[3] per (src-view, batch)
__global__ void proj_kernel(const float* __restrict__ K, const float* __restrict__ c2w,
                            float* __restrict__ proj_out) {
    int t = blockIdx.x * blockDim.x + threadIdx.x;
    if (t >= (V_-1) * B_) return;
    int vv = t / B_;      // 0-based src view
    int b  = t % B_;
    int v  = vv + 1;
    double sc[16], rc[16];
    for (int i = 0; i < 16; i++) {
        sc[i] = (double)c2w[((size_t)v * B_ + b) * 16 + i];
        rc[i] = (double)c2w[((size_t)0 * B_ + b) * 16 + i];
    }
    double sw[16], rw[16];
    inv4(sc, sw);
    inv4(rc, rw);
    double sK[16], rK[16];
    for (int i = 0; i < 16; i++) { sK[i] = sw[i]; rK[i] = rw[i]; }
    for (int r = 0; r < 3; r++)
        for (int c = 0; c < 3; c++) {
            sK[r*4+c] = (double)K[((size_t)v * B_ + b) * 9 + r*3 + c];
            rK[r*4+c] = (double)K[((size_t)0 * B_ + b) * 9 + r*3 + c];
        }
    double sp[16], rp[16], rpi[16], P[16];
    mm4(sK, sw, sp);          // src_proj
    mm4(rK, rw, rp);          // ref_proj
    inv4(rp, rpi);
    mm4(sp, rpi, P);          // proj
    float* o = proj_out + (size_t)t * 12;
    for (int r = 0; r < 3; r++)
        for (int c = 0; c < 3; c++) o[r*3+c] = (float)P[r*4+c];
    for (int r = 0; r < 3; r++) o[9+r] = (float)P[r*4+3];
}

// features (V,B,C,H,W) -> featT (V,B,H,W,C)
__global__ void __launch_bounds__(256) transpose_kernel(const float* __restrict__ feat,
                                                        float* __restrict__ featT) {
    int idx = blockIdx.x * 256 + threadIdx.x;
    if (idx >= NFEATT_) return;
    int c  = idx & (C_ - 1);
    int x  = (idx / C_) % W_;
    int y  = (idx / (C_ * W_)) % H_;
    int vb = idx / (C_ * W_ * H_);
    featT[idx] = feat[((size_t)vb * C_ + c) * HW_ + y * W_ + x];
}

// cost (B,D,H,W): min over src views of (ref . bilinear(src)) * sigmoid(unc)
__global__ void __launch_bounds__(256) cost_kernel(const float* __restrict__ featT,
                                                   const float* __restrict__ depth,
                                                   const float* __restrict__ unc,
                                                   const float* __restrict__ proj,
                                                   float* __restrict__ cost) {
    int idx = blockIdx.x * 256 + threadIdx.x;
    if (idx >= NCOST_) return;
    int x = idx % W_;
    int y = (idx / W_) % H_;
    int b = idx / (W_ * H_ * D_);
    float dep = depth[idx];

    const float4* refp = (const float4*)(featT + ((size_t)(b * H_ + y) * W_ + x) * C_);
    float4 ref4[8];
#pragma unroll
    for (int i = 0; i < 8; i++) ref4[i] = refp[i];

    float fx = (float)x, fy = (float)y;
    float dv[2];
#pragma unroll
    for (int v = 0; v < 2; v++) {
        const float* P = proj + ((size_t)v * B_ + b) * 12;
        float rx = P[0]*fx + P[1]*fy + P[2];
        float ry = P[3]*fx + P[4]*fy + P[5];
        float rz = P[6]*fx + P[7]*fy + P[8];
        float px = rx * dep + P[9];
        float py = ry * dep + P[10];
        float pz = rz * dep + P[11];
        float t0 = px / pz;
        float t1 = py / pz;
        float gx = t0 / ((W_ - 1) * 0.5f) - 1.0f;
        float gy = t1 / ((H_ - 1) * 0.5f) - 1.0f;
        float ix = ((gx + 1.0f) * W_ - 1.0f) * 0.5f;
        float iy = ((gy + 1.0f) * H_ - 1.0f) * 0.5f;
        float x0f = floorf(ix), y0f = floorf(iy);
        float wx = ix - x0f, wy = iy - y0f;
        int x0 = (int)x0f, y0 = (int)y0f;
        int x1 = x0 + 1, y1 = y0 + 1;
        bool vx0 = (x0 >= 0) && (x0 <= W_ - 1);
        bool vx1 = (x1 >= 0) && (x1 <= W_ - 1);
        bool vy0 = (y0 >= 0) && (y0 <= H_ - 1);
        bool vy1 = (y1 >= 0) && (y1 <= H_ - 1);
        float w00 = (vx0 && vy0) ? (1.0f - wx) * (1.0f - wy) : 0.0f;
        float w01 = (vx1 && vy0) ? wx * (1.0f - wy) : 0.0f;
        float w10 = (vx0 && vy1) ? (1.0f - wx) * wy : 0.0f;
        float w11 = (vx1 && vy1) ? wx * wy : 0.0f;
        int xc0 = min(max(x0, 0), W_ - 1), xc1 = min(max(x1, 0), W_ - 1);
        int yc0 = min(max(y0, 0), H_ - 1), yc1 = min(max(y1, 0), H_ - 1);
        size_t base = ((size_t)(v + 1) * B_ + b) * (size_t)HW_;
        const float4* f00 = (const float4*)(featT + (base + yc0 * W_ + xc0) * C_);
        const float4* f01 = (const float4*)(featT + (base + yc0 * W_ + xc1) * C_);
        const float4* f10 = (const float4*)(featT + (base + yc1 * W_ + xc0) * C_);
        const float4* f11 = (const float4*)(featT + (base + yc1 * W_ + xc1) * C_);
        float acc = 0.0f;
#pragma unroll
        for (int i = 0; i < 8; i++) {
            float4 a = f00[i], bq = f01[i], cq = f10[i], dq = f11[i];
            float sx = w00*a.x + w01*bq.x + w10*cq.x + w11*dq.x;
            float sy = w00*a.y + w01*bq.y + w10*cq.y + w11*dq.y;
            float sz = w00*a.z + w01*bq.z + w10*cq.z + w11*dq.z;
            float sw = w00*a.w + w01*bq.w + w10*cq.w + w11*dq.w;
            acc += ref4[i].x*sx + ref4[i].y*sy + ref4[i].z*sz + ref4[i].w*sw;
        }
        dv[v] = acc;
    }
    float u = unc[(b * H_ + y) * W_ + x];
    float sig = 1.0f / (1.0f + expf(-u));
    cost[idx] = fminf(dv[0], dv[1]) * sig;
}

// w_feat: per-pixel softmax over 25 neighbor dots; stored as (25, B*H*W)
__global__ void __launch_bounds__(256) wfeat_kernel(const float* __restrict__ featT,
                                                    float* __restrict__ wfeat) {
    int idx = blockIdx.x * 256 + threadIdx.x;
    if (idx >= NPIX_) return;
    int x = idx % W_;
    int y = (idx / W_) % H_;
    int b = idx / (W_ * H_);
    const float4* refp = (const float4*)(featT + ((size_t)(b * H_ + y) * W_ + x) * C_);
    float4 r[8];
#pragma unroll
    for (int i = 0; i < 8; i++) r[i] = refp[i];
    float logit[25];
#pragma unroll
    for (int k = 0; k < 25; k++) {
        int dy = k / 5 - 2, dx = k % 5 - 2;
        int ny = y + dy, nx = x + dx;
        float acc = 0.0f;
        if (ny >= 0 && ny < H_ && nx >= 0 && nx < W_) {
            const float4* np_ = (const float4*)(featT + ((size_t)(b * H_ + ny) * W_ + nx) * C_);
#pragma unroll
            for (int i = 0; i < 8; i++) {
                float4 q = np_[i];
                acc += r[i].x*q.x + r[i].y*q.y + r[i].z*q.z + r[i].w*q.w;
            }
        }
        logit[k] = acc;
    }
    float m = logit[0];
#pragma unroll
    for (int k = 1; k < 25; k++) m = fmaxf(m, logit[k]);
    float s = 0.0f;
#pragma unroll
    for (int k = 0; k < 25; k++) { logit[k] = expf(logit[k] - m); s += logit[k]; }
    float inv_s = 1.0f / s;
#pragma unroll
    for (int k = 0; k < 25; k++) wfeat[(size_t)k * NPIX_ + idx] = logit[k] * inv_s;
}

// agg (B,D,H,W)
__global__ void __launch_bounds__(256) agg_kernel(const float* __restrict__ depth,
                                                  const float* __restrict__ cost,
                                                  const float* __restrict__ wfeat,
                                                  float* __restrict__ agg) {
    int idx = blockIdx.x * 256 + threadIdx.x;
    if (idx >= NCOST_) return;
    int x = idx % W_;
    int y = (idx / W_) % H_;
    int d = (idx / (W_ * H_)) % D_;
    int b = idx / (W_ * H_ * D_);
    float dc = depth[idx];
    size_t dslice = ((size_t)b * D_ + d) * HW_;
    int pix = (b * H_ + y) * W_ + x;

    float wd[25];
    float m1 = -1e30f;
#pragma unroll
    for (int k = 0; k < 25; k++) {
        int dy = k / 5 - 2, dx = k % 5 - 2;
        int ny = y + dy, nx = x + dx;
        bool ok = (ny >= 0 && ny < H_ && nx >= 0 && nx < W_);
        float nd = ok ? depth[dslice + ny * W_ + nx] : 0.0f;
        float l = -fabsf(nd - dc);
        wd[k] = l;
        m1 = fmaxf(m1, l);
    }
    float s1 = 0.0f;
#pragma unroll
    for (int k = 0; k < 25; k++) { wd[k] = expf(wd[k] - m1); s1 += wd[k]; }
    float inv_s1 = 1.0f / s1;

    float lg[25];
    float m2 = -1e30f;
#pragma unroll
    for (int k = 0; k < 25; k++) {
        float wf = wfeat[(size_t)k * NPIX_ + pix];
        float l = (wd[k] * inv_s1) * wf;
        lg[k] = l;
        m2 = fmaxf(m2, l);
    }
    float s2 = 0.0f;
    float acc = 0.0f;
#pragma unroll
    for (int k = 0; k < 25; k++) {
        float e = expf(lg[k] - m2);
        s2 += e;
        int dy = k / 5 - 2, dx = k % 5 - 2;
        int ny = y + dy, nx = x + dx;
        bool ok = (ny >= 0 && ny < H_ && nx >= 0 && nx < W_);
        float cv = ok ? cost[dslice + ny * W_ + nx] : 0.0f;
        acc += cv * e;
    }
    agg[idx] = acc / s2;
}

// softmax over D + expectation -> out (B,H,W)
__global__ void __launch_bounds__(256) final_kernel(const float* __restrict__ agg,
                                                    const float* __restrict__ depth,
                                                    float* __restrict__ out) {
    int idx = blockIdx.x * 256 + threadIdx.x;
    if (idx >= NPIX_) return;
    int x = idx % W_;
    int y = (idx / W_) % H_;
    int b = idx / (W_ * H_);
    float a[D_];
    float m = -1e30f;
#pragma unroll
    for (int d = 0; d < D_; d++) {
        a[d] = agg[((size_t)(b * D_ + d) * H_ + y) * W_ + x];
        m = fmaxf(m, a[d]);
    }
    float s = 0.0f, ws = 0.0f;
#pragma unroll
    for (int d = 0; d < D_; d++) {
        float e = expf(a[d] - m);
        s += e;
        ws += e * depth[((size_t)(b * D_ + d) * H_ + y) * W_ + x];
    }
    out[idx] = ws / s;
}

extern "C" void kernel_launch(void* const* d_in, const int* in_sizes, int n_in,
                              void* d_out, int out_size, void* d_ws, size_t ws_size,
                              hipStream_t stream) {
    const float* features = (const float*)d_in[0];  // (3,2,32,128,160)
    const float* intr     = (const float*)d_in[1];  // (3,2,3,3)
    const float* c2w      = (const float*)d_in[2];  // (3,2,4,4)
    const float* depth    = (const float*)d_in[3];  // (2,32,128,160)
    const float* unc      = (const float*)d_in[4];  // (2,128,160)
    float* out = (float*)d_out;

    float* ws    = (float*)d_ws;
    float* featT = ws;                          // NFEATT_
    float* cost  = featT + NFEATT_;             // NCOST_
    float* wfeat = cost + NCOST_;               // 25*NPIX_
    float* agg   = wfeat + (size_t)25 * NPIX_;  // NCOST_
    float* proj  = agg + NCOST_;                // 48

    hipLaunchKernelGGL(proj_kernel, dim3(1), dim3(64), 0, stream, intr, c2w, proj);
    hipLaunchKernelGGL(transpose_kernel, dim3(NFEATT_ / 256), dim3(256), 0, stream, features, featT);
    hipLaunchKernelGGL(cost_kernel, dim3(NCOST_ / 256), dim3(256), 0, stream, featT, depth, unc, proj, cost);
    hipLaunchKernelGGL(wfeat_kernel, dim3(NPIX_ / 256), dim3(256), 0, stream, featT, wfeat);
    hipLaunchKernelGGL(agg_kernel, dim3(NCOST_ / 256), dim3(256), 0, stream, depth, cost, wfeat, agg);
    hipLaunchKernelGGL(final_kernel, dim3(NPIX_ / 256), dim3(256), 0, stream, agg, depth, out);
}

// Round 2
// 156.405 us; speedup vs baseline: 1.5689x; 1.5689x over previous
//
#include <hip/hip_runtime.h>
#include <math.h>

#define V_ 3
#define B_ 2
#define C_ 32
#define D_ 32
#define H_ 128
#define W_ 160
#define HW_ (H_*W_)
#define NPIX_ (B_*H_*W_)              // 40960
#define NCOST_ (B_*D_*H_*W_)          // 1310720
#define NFEATT_ (V_*B_*H_*W_*C_)      // 3932160

// ---------------- 4x4 double inverse (adjugate) ----------------
__device__ __forceinline__ void inv4(const double* m, double* o) {
    double inv[16];
    inv[0]  =  m[5]*m[10]*m[15] - m[5]*m[11]*m[14] - m[9]*m[6]*m[15] + m[9]*m[7]*m[14] + m[13]*m[6]*m[11] - m[13]*m[7]*m[10];
    inv[4]  = -m[4]*m[10]*m[15] + m[4]*m[11]*m[14] + m[8]*m[6]*m[15] - m[8]*m[7]*m[14] - m[12]*m[6]*m[11] + m[12]*m[7]*m[10];
    inv[8]  =  m[4]*m[9]*m[15]  - m[4]*m[11]*m[13] - m[8]*m[5]*m[15] + m[8]*m[7]*m[13] + m[12]*m[5]*m[11] - m[12]*m[7]*m[9];
    inv[12] = -m[4]*m[9]*m[14]  + m[4]*m[10]*m[13] + m[8]*m[5]*m[14] - m[8]*m[6]*m[13] - m[12]*m[5]*m[10] + m[12]*m[6]*m[9];
    inv[1]  = -m[1]*m[10]*m[15] + m[1]*m[11]*m[14] + m[9]*m[2]*m[15] - m[9]*m[3]*m[14] - m[13]*m[2]*m[11] + m[13]*m[3]*m[10];
    inv[5]  =  m[0]*m[10]*m[15] - m[0]*m[11]*m[14] - m[8]*m[2]*m[15] + m[8]*m[3]*m[14] + m[12]*m[2]*m[11] - m[12]*m[3]*m[10];
    inv[9]  = -m[0]*m[9]*m[15]  + m[0]*m[11]*m[13] + m[8]*m[1]*m[15] - m[8]*m[3]*m[13] - m[12]*m[1]*m[11] + m[12]*m[3]*m[9];
    inv[13] =  m[0]*m[9]*m[14]  - m[0]*m[10]*m[13] - m[8]*m[1]*m[14] + m[8]*m[2]*m[13] + m[12]*m[1]*m[10] - m[12]*m[2]*m[9];
    inv[2]  =  m[1]*m[6]*m[15]  - m[1]*m[7]*m[14]  - m[5]*m[2]*m[15] + m[5]*m[3]*m[14] + m[13]*m[2]*m[7]  - m[13]*m[3]*m[6];
    inv[6]  = -m[0]*m[6]*m[15]  + m[0]*m[7]*m[14]  + m[4]*m[2]*m[15] - m[4]*m[3]*m[14] - m[12]*m[2]*m[7]  + m[12]*m[3]*m[6];
    inv[10] =  m[0]*m[5]*m[15]  - m[0]*m[7]*m[13]  - m[4]*m[1]*m[15] + m[4]*m[3]*m[13] + m[12]*m[1]*m[7]  - m[12]*m[3]*m[5];
    inv[14] = -m[0]*m[5]*m[14]  + m[0]*m[6]*m[13]  + m[4]*m[1]*m[14] - m[4]*m[2]*m[13] - m[12]*m[1]*m[6]  + m[12]*m[2]*m[5];
    inv[3]  = -m[1]*m[6]*m[11]  + m[1]*m[7]*m[10]  + m[5]*m[2]*m[11] - m[5]*m[3]*m[10] - m[9]*m[2]*m[7]   + m[9]*m[3]*m[6];
    inv[7]  =  m[0]*m[6]*m[11]  - m[0]*m[7]*m[10]  - m[4]*m[2]*m[11] + m[4]*m[3]*m[10] + m[8]*m[2]*m[7]   - m[8]*m[3]*m[6];
    inv[11] = -m[0]*m[5]*m[11]  + m[0]*m[7]*m[9]   + m[4]*m[1]*m[11] - m[4]*m[3]*m[9]  - m[8]*m[1]*m[7]   + m[8]*m[3]*m[5];
    inv[15] =  m[0]*m[5]*m[10]  - m[0]*m[6]*m[9]   - m[4]*m[1]*m[10] + m[4]*m[2]*m[9]  + m[8]*m[1]*m[6]   - m[8]*m[2]*m[5];
    double det = m[0]*inv[0] + m[1]*inv[4] + m[2]*inv[8] + m[3]*inv[12];
    det = 1.0 / det;
    for (int i = 0; i < 16; i++) o[i] = inv[i] * det;
}

__device__ __forceinline__ void mm4(const double* A, const double* Bm, double* Cm) {
    for (int r = 0; r < 4; r++)
        for (int c = 0; c < 4; c++) {
            double s = 0.0;
            for (int k = 0; k < 4; k++) s += A[r*4+k] * Bm[k*4+c];
            Cm[r*4+c] = s;
        }
}

// proj_out: (V-1, B, 12) = rot[9] + trans[3] per (src-view, batch)
__global__ void proj_kernel(const float* __restrict__ K, const float* __restrict__ c2w,
                            float* __restrict__ proj_out) {
    int t = blockIdx.x * blockDim.x + threadIdx.x;
    if (t >= (V_-1) * B_) return;
    int vv = t / B_;
    int b  = t % B_;
    int v  = vv + 1;
    double sc[16], rc[16];
    for (int i = 0; i < 16; i++) {
        sc[i] = (double)c2w[((size_t)v * B_ + b) * 16 + i];
        rc[i] = (double)c2w[((size_t)0 * B_ + b) * 16 + i];
    }
    double sw[16], rw[16];
    inv4(sc, sw);
    inv4(rc, rw);
    double sK[16], rK[16];
    for (int i = 0; i < 16; i++) { sK[i] = sw[i]; rK[i] = rw[i]; }
    for (int r = 0; r < 3; r++)
        for (int c = 0; c < 3; c++) {
            sK[r*4+c] = (double)K[((size_t)v * B_ + b) * 9 + r*3 + c];
            rK[r*4+c] = (double)K[((size_t)0 * B_ + b) * 9 + r*3 + c];
        }
    double sp[16], rp[16], rpi[16], P[16];
    mm4(sK, sw, sp);
    mm4(rK, rw, rp);
    inv4(rp, rpi);
    mm4(sp, rpi, P);
    float* o = proj_out + (size_t)t * 12;
    for (int r = 0; r < 3; r++)
        for (int c = 0; c < 3; c++) o[r*3+c] = (float)P[r*4+c];
    for (int r = 0; r < 3; r++) o[9+r] = (float)P[r*4+3];
}

// features (V,B,C,H,W) -> featT (V,B,H,W,C) via LDS tile (32c x 32x per block)
__global__ void __launch_bounds__(256) transpose_kernel(const float* __restrict__ feat,
                                                        float* __restrict__ featT) {
    __shared__ float lds[32][33];
    int bid = blockIdx.x;
    int xt = bid % (W_ / 32);
    int y  = (bid / (W_ / 32)) % H_;
    int vb = bid / ((W_ / 32) * H_);
    int x0 = xt * 32;
    int tid = threadIdx.x;
    int xl = tid & 31;
    int ch = tid >> 5;   // 0..7
#pragma unroll
    for (int it = 0; it < 4; it++) {
        int c = it * 8 + ch;
        lds[c][xl] = feat[((size_t)(vb * C_ + c) * H_ + y) * W_ + x0 + xl];
    }
    __syncthreads();
    int c4 = tid & 7;
    int xw = tid >> 3;   // 0..31
    float4 o;
    o.x = lds[c4*4+0][xw];
    o.y = lds[c4*4+1][xw];
    o.z = lds[c4*4+2][xw];
    o.w = lds[c4*4+3][xw];
    *(float4*)(featT + ((size_t)(vb * H_ + y) * W_ + x0 + xw) * C_ + c4 * 4) = o;
}

// cost (B,D,H,W): 8 lanes per output element, channel-quarter split
__global__ void __launch_bounds__(256) cost_kernel(const float* __restrict__ featT,
                                                   const float* __restrict__ depth,
                                                   const float* __restrict__ unc,
                                                   const float* __restrict__ proj,
                                                   float* __restrict__ cost) {
    int tid = threadIdx.x;
    int g  = tid >> 3;
    int c4 = tid & 7;
    int idx = blockIdx.x * 32 + g;
    int x = idx % W_;
    int y = (idx / W_) % H_;
    int b = idx / (W_ * H_ * D_);
    float dep = depth[idx];

    const float4 ref4 = *(const float4*)(featT + ((size_t)(b * H_ + y) * W_ + x) * C_ + c4 * 4);

    float fx = (float)x, fy = (float)y;
    float dv[2];
#pragma unroll
    for (int v = 0; v < 2; v++) {
        const float* P = proj + ((size_t)v * B_ + b) * 12;
        float rx = P[0]*fx + P[1]*fy + P[2];
        float ry = P[3]*fx + P[4]*fy + P[5];
        float rz = P[6]*fx + P[7]*fy + P[8];
        float px = rx * dep + P[9];
        float py = ry * dep + P[10];
        float pz = rz * dep + P[11];
        float t0 = px / pz;
        float t1 = py / pz;
        float gx = t0 / ((W_ - 1) * 0.5f) - 1.0f;
        float gy = t1 / ((H_ - 1) * 0.5f) - 1.0f;
        float ix = ((gx + 1.0f) * W_ - 1.0f) * 0.5f;
        float iy = ((gy + 1.0f) * H_ - 1.0f) * 0.5f;
        float x0f = floorf(ix), y0f = floorf(iy);
        float wx = ix - x0f, wy = iy - y0f;
        int x0 = (int)x0f, y0 = (int)y0f;
        int x1 = x0 + 1, y1 = y0 + 1;
        bool vx0 = (x0 >= 0) && (x0 <= W_ - 1);
        bool vx1 = (x1 >= 0) && (x1 <= W_ - 1);
        bool vy0 = (y0 >= 0) && (y0 <= H_ - 1);
        bool vy1 = (y1 >= 0) && (y1 <= H_ - 1);
        float w00 = (vx0 && vy0) ? (1.0f - wx) * (1.0f - wy) : 0.0f;
        float w01 = (vx1 && vy0) ? wx * (1.0f - wy) : 0.0f;
        float w10 = (vx0 && vy1) ? (1.0f - wx) * wy : 0.0f;
        float w11 = (vx1 && vy1) ? wx * wy : 0.0f;
        int xc0 = min(max(x0, 0), W_ - 1), xc1 = min(max(x1, 0), W_ - 1);
        int yc0 = min(max(y0, 0), H_ - 1), yc1 = min(max(y1, 0), H_ - 1);
        size_t base = ((size_t)(v + 1) * B_ + b) * (size_t)HW_;
        const float4 a  = *(const float4*)(featT + (base + yc0 * W_ + xc0) * C_ + c4 * 4);
        const float4 bq = *(const float4*)(featT + (base + yc0 * W_ + xc1) * C_ + c4 * 4);
        const float4 cq = *(const float4*)(featT + (base + yc1 * W_ + xc0) * C_ + c4 * 4);
        const float4 dq = *(const float4*)(featT + (base + yc1 * W_ + xc1) * C_ + c4 * 4);
        float sx = w00*a.x + w01*bq.x + w10*cq.x + w11*dq.x;
        float sy = w00*a.y + w01*bq.y + w10*cq.y + w11*dq.y;
        float sz = w00*a.z + w01*bq.z + w10*cq.z + w11*dq.z;
        float sw = w00*a.w + w01*bq.w + w10*cq.w + w11*dq.w;
        float p = ref4.x*sx + ref4.y*sy + ref4.z*sz + ref4.w*sw;
        p += __shfl_xor(p, 1);
        p += __shfl_xor(p, 2);
        p += __shfl_xor(p, 4);
        dv[v] = p;
    }
    if (c4 == 0) {
        float u = unc[(b * H_ + y) * W_ + x];
        float sig = 1.0f / (1.0f + expf(-u));
        cost[idx] = fminf(dv[0], dv[1]) * sig;
    }
}

// w_feat: 8 lanes per pixel; softmax over 25 neighbor dots; stored (25, B*H*W)
__global__ void __launch_bounds__(256) wfeat_kernel(const float* __restrict__ featT,
                                                    float* __restrict__ wfeat) {
    int tid = threadIdx.x;
    int g  = tid >> 3;
    int c4 = tid & 7;
    int pix = blockIdx.x * 32 + g;
    int x = pix % W_;
    int y = (pix / W_) % H_;
    int b = pix / (W_ * H_);
    const float4 r = *(const float4*)(featT + (size_t)pix * C_ + c4 * 4);
    float logit[25];
#pragma unroll
    for (int k = 0; k < 25; k++) {
        int dy = k / 5 - 2, dx = k % 5 - 2;
        int ny = y + dy, nx = x + dx;
        float p = 0.0f;
        if (ny >= 0 && ny < H_ && nx >= 0 && nx < W_) {
            const float4 q = *(const float4*)(featT + ((size_t)(b * H_ + ny) * W_ + nx) * C_ + c4 * 4);
            p = r.x*q.x + r.y*q.y + r.z*q.z + r.w*q.w;
        }
        p += __shfl_xor(p, 1);
        p += __shfl_xor(p, 2);
        p += __shfl_xor(p, 4);
        logit[k] = p;
    }
    float m = logit[0];
#pragma unroll
    for (int k = 1; k < 25; k++) m = fmaxf(m, logit[k]);
    float s = 0.0f;
#pragma unroll
    for (int k = 0; k < 25; k++) { logit[k] = expf(logit[k] - m); s += logit[k]; }
    float inv_s = 1.0f / s;
    // lane c4 writes k = c4, c4+8, c4+16; lane 0 also writes k=24
#pragma unroll
    for (int t = 0; t < 3; t++) {
        int k = c4 + 8 * t;
        wfeat[(size_t)k * NPIX_ + pix] = logit[k] * inv_s;
    }
    if (c4 == 0) wfeat[(size_t)24 * NPIX_ + pix] = logit[24] * inv_s;
}

// agg (B,D,H,W)
__global__ void __launch_bounds__(256) agg_kernel(const float* __restrict__ depth,
                                                  const float* __restrict__ cost,
                                                  const float* __restrict__ wfeat,
                                                  float* __restrict__ agg) {
    int idx = blockIdx.x * 256 + threadIdx.x;
    if (idx >= NCOST_) return;
    int x = idx % W_;
    int y = (idx / W_) % H_;
    int d = (idx / (W_ * H_)) % D_;
    int b = idx / (W_ * H_ * D_);
    float dc = depth[idx];
    size_t dslice = ((size_t)b * D_ + d) * HW_;
    int pix = (b * H_ + y) * W_ + x;

    float wd[25];
    float m1 = -1e30f;
#pragma unroll
    for (int k = 0; k < 25; k++) {
        int dy = k / 5 - 2, dx = k % 5 - 2;
        int ny = y + dy, nx = x + dx;
        bool ok = (ny >= 0 && ny < H_ && nx >= 0 && nx < W_);
        float nd = ok ? depth[dslice + ny * W_ + nx] : 0.0f;
        float l = -fabsf(nd - dc);
        wd[k] = l;
        m1 = fmaxf(m1, l);
    }
    float s1 = 0.0f;
#pragma unroll
    for (int k = 0; k < 25; k++) { wd[k] = expf(wd[k] - m1); s1 += wd[k]; }
    float inv_s1 = 1.0f / s1;

    float lg[25];
    float m2 = -1e30f;
#pragma unroll
    for (int k = 0; k < 25; k++) {
        float wf = wfeat[(size_t)k * NPIX_ + pix];
        float l = (wd[k] * inv_s1) * wf;
        lg[k] = l;
        m2 = fmaxf(m2, l);
    }
    float s2 = 0.0f;
    float acc = 0.0f;
#pragma unroll
    for (int k = 0; k < 25; k++) {
        float e = expf(lg[k] - m2);
        s2 += e;
        int dy = k / 5 - 2, dx = k % 5 - 2;
        int ny = y + dy, nx = x + dx;
        bool ok = (ny >= 0 && ny < H_ && nx >= 0 && nx < W_);
        float cv = ok ? cost[dslice + ny * W_ + nx] : 0.0f;
        acc += cv * e;
    }
    agg[idx] = acc / s2;
}

// softmax over D + expectation -> out (B,H,W)
__global__ void __launch_bounds__(256) final_kernel(const float* __restrict__ agg,
                                                    const float* __restrict__ depth,
                                                    float* __restrict__ out) {
    int idx = blockIdx.x * 256 + threadIdx.x;
    if (idx >= NPIX_) return;
    int x = idx % W_;
    int y = (idx / W_) % H_;
    int b = idx / (W_ * H_);
    float a[D_];
    float m = -1e30f;
#pragma unroll
    for (int d = 0; d < D_; d++) {
        a[d] = agg[((size_t)(b * D_ + d) * H_ + y) * W_ + x];
        m = fmaxf(m, a[d]);
    }
    float s = 0.0f, ws = 0.0f;
#pragma unroll
    for (int d = 0; d < D_; d++) {
        float e = expf(a[d] - m);
        s += e;
        ws += e * depth[((size_t)(b * D_ + d) * H_ + y) * W_ + x];
    }
    out[idx] = ws / s;
}

extern "C" void kernel_launch(void* const* d_in, const int* in_sizes, int n_in,
                              void* d_out, int out_size, void* d_ws, size_t ws_size,
                              hipStream_t stream) {
    const float* features = (const float*)d_in[0];  // (3,2,32,128,160)
    const float* intr     = (const float*)d_in[1];  // (3,2,3,3)
    const float* c2w      = (const float*)d_in[2];  // (3,2,4,4)
    const float* depth    = (const float*)d_in[3];  // (2,32,128,160)
    const float* unc      = (const float*)d_in[4];  // (2,128,160)
    float* out = (float*)d_out;

    float* ws    = (float*)d_ws;
    float* featT = ws;                          // NFEATT_
    float* cost  = featT + NFEATT_;             // NCOST_
    float* wfeat = cost + NCOST_;               // 25*NPIX_
    float* agg   = wfeat + (size_t)25 * NPIX_;  // NCOST_
    float* proj  = agg + NCOST_;                // 48

    hipLaunchKernelGGL(proj_kernel, dim3(1), dim3(64), 0, stream, intr, c2w, proj);
    hipLaunchKernelGGL(transpose_kernel, dim3(V_ * B_ * H_ * (W_ / 32)), dim3(256), 0, stream, features, featT);
    hipLaunchKernelGGL(cost_kernel, dim3(NCOST_ / 32), dim3(256), 0, stream, featT, depth, unc, proj, cost);
    hipLaunchKernelGGL(wfeat_kernel, dim3(NPIX_ / 32), dim3(256), 0, stream, featT, wfeat);
    hipLaunchKernelGGL(agg_kernel, dim3(NCOST_ / 256), dim3(256), 0, stream, depth, cost, wfeat, agg);
    hipLaunchKernelGGL(final_kernel, dim3(NPIX_ / 256), dim3(256), 0, stream, agg, depth, out);
}

// Round 3
// 125.368 us; speedup vs baseline: 1.9573x; 1.2476x over previous
//
#include <hip/hip_runtime.h>
#include <math.h>

#define V_ 3
#define B_ 2
#define C_ 32
#define D_ 32
#define H_ 128
#define W_ 160
#define HW_ (H_*W_)
#define NPIX_ (B_*H_*W_)              // 40960
#define NCOST_ (B_*D_*H_*W_)          // 1310720
#define NFEATT_ (V_*B_*H_*W_*C_)      // 3932160

// ---------------- 4x4 double inverse (adjugate) ----------------
__device__ __forceinline__ void inv4(const double* m, double* o) {
    double inv[16];
    inv[0]  =  m[5]*m[10]*m[15] - m[5]*m[11]*m[14] - m[9]*m[6]*m[15] + m[9]*m[7]*m[14] + m[13]*m[6]*m[11] - m[13]*m[7]*m[10];
    inv[4]  = -m[4]*m[10]*m[15] + m[4]*m[11]*m[14] + m[8]*m[6]*m[15] - m[8]*m[7]*m[14] - m[12]*m[6]*m[11] + m[12]*m[7]*m[10];
    inv[8]  =  m[4]*m[9]*m[15]  - m[4]*m[11]*m[13] - m[8]*m[5]*m[15] + m[8]*m[7]*m[13] + m[12]*m[5]*m[11] - m[12]*m[7]*m[9];
    inv[12] = -m[4]*m[9]*m[14]  + m[4]*m[10]*m[13] + m[8]*m[5]*m[14] - m[8]*m[6]*m[13] - m[12]*m[5]*m[10] + m[12]*m[6]*m[9];
    inv[1]  = -m[1]*m[10]*m[15] + m[1]*m[11]*m[14] + m[9]*m[2]*m[15] - m[9]*m[3]*m[14] - m[13]*m[2]*m[11] + m[13]*m[3]*m[10];
    inv[5]  =  m[0]*m[10]*m[15] - m[0]*m[11]*m[14] - m[8]*m[2]*m[15] + m[8]*m[3]*m[14] + m[12]*m[2]*m[11] - m[12]*m[3]*m[10];
    inv[9]  = -m[0]*m[9]*m[15]  + m[0]*m[11]*m[13] + m[8]*m[1]*m[15] - m[8]*m[3]*m[13] - m[12]*m[1]*m[11] + m[12]*m[3]*m[9];
    inv[13] =  m[0]*m[9]*m[14]  - m[0]*m[10]*m[13] - m[8]*m[1]*m[14] + m[8]*m[2]*m[13] + m[12]*m[1]*m[10] - m[12]*m[2]*m[9];
    inv[2]  =  m[1]*m[6]*m[15]  - m[1]*m[7]*m[14]  - m[5]*m[2]*m[15] + m[5]*m[3]*m[14] + m[13]*m[2]*m[7]  - m[13]*m[3]*m[6];
    inv[6]  = -m[0]*m[6]*m[15]  + m[0]*m[7]*m[14]  + m[4]*m[2]*m[15] - m[4]*m[3]*m[14] - m[12]*m[2]*m[7]  + m[12]*m[3]*m[6];
    inv[10] =  m[0]*m[5]*m[15]  - m[0]*m[7]*m[13]  - m[4]*m[1]*m[15] + m[4]*m[3]*m[13] + m[12]*m[1]*m[7]  - m[12]*m[3]*m[5];
    inv[14] = -m[0]*m[5]*m[14]  + m[0]*m[6]*m[13]  + m[4]*m[1]*m[14] - m[4]*m[2]*m[13] - m[12]*m[1]*m[6]  + m[12]*m[2]*m[5];
    inv[3]  = -m[1]*m[6]*m[11]  + m[1]*m[7]*m[10]  + m[5]*m[2]*m[11] - m[5]*m[3]*m[10] - m[9]*m[2]*m[7]   + m[9]*m[3]*m[6];
    inv[7]  =  m[0]*m[6]*m[11]  - m[0]*m[7]*m[10]  - m[4]*m[2]*m[11] + m[4]*m[3]*m[10] + m[8]*m[2]*m[7]   - m[8]*m[3]*m[6];
    inv[11] = -m[0]*m[5]*m[11]  + m[0]*m[7]*m[9]   + m[4]*m[1]*m[11] - m[4]*m[3]*m[9]  - m[8]*m[1]*m[7]   + m[8]*m[3]*m[5];
    inv[15] =  m[0]*m[5]*m[10]  - m[0]*m[6]*m[9]   - m[4]*m[1]*m[10] + m[4]*m[2]*m[9]  + m[8]*m[1]*m[6]   - m[8]*m[2]*m[5];
    double det = m[0]*inv[0] + m[1]*inv[4] + m[2]*inv[8] + m[3]*inv[12];
    det = 1.0 / det;
    for (int i = 0; i < 16; i++) o[i] = inv[i] * det;
}

__device__ __forceinline__ void mm4(const double* A, const double* Bm, double* Cm) {
    for (int r = 0; r < 4; r++)
        for (int c = 0; c < 4; c++) {
            double s = 0.0;
            for (int k = 0; k < 4; k++) s += A[r*4+k] * Bm[k*4+c];
            Cm[r*4+c] = s;
        }
}

// proj_out: (V-1, B, 12) = rot[9] + trans[3] per (src-view, batch)
__global__ void proj_kernel(const float* __restrict__ K, const float* __restrict__ c2w,
                            float* __restrict__ proj_out) {
    int t = blockIdx.x * blockDim.x + threadIdx.x;
    if (t >= (V_-1) * B_) return;
    int vv = t / B_;
    int b  = t % B_;
    int v  = vv + 1;
    double sc[16], rc[16];
    for (int i = 0; i < 16; i++) {
        sc[i] = (double)c2w[((size_t)v * B_ + b) * 16 + i];
        rc[i] = (double)c2w[((size_t)0 * B_ + b) * 16 + i];
    }
    double sw[16], rw[16];
    inv4(sc, sw);
    inv4(rc, rw);
    double sK[16], rK[16];
    for (int i = 0; i < 16; i++) { sK[i] = sw[i]; rK[i] = rw[i]; }
    for (int r = 0; r < 3; r++)
        for (int c = 0; c < 3; c++) {
            sK[r*4+c] = (double)K[((size_t)v * B_ + b) * 9 + r*3 + c];
            rK[r*4+c] = (double)K[((size_t)0 * B_ + b) * 9 + r*3 + c];
        }
    double sp[16], rp[16], rpi[16], P[16];
    mm4(sK, sw, sp);
    mm4(rK, rw, rp);
    inv4(rp, rpi);
    mm4(sp, rpi, P);
    float* o = proj_out + (size_t)t * 12;
    for (int r = 0; r < 3; r++)
        for (int c = 0; c < 3; c++) o[r*3+c] = (float)P[r*4+c];
    for (int r = 0; r < 3; r++) o[9+r] = (float)P[r*4+3];
}

// features (V,B,C,H,W) -> featT (V,B,H,W,C) via LDS tile (32c x 32x per block)
__global__ void __launch_bounds__(256) transpose_kernel(const float* __restrict__ feat,
                                                        float* __restrict__ featT) {
    __shared__ float lds[32][33];
    int bid = blockIdx.x;
    int xt = bid % (W_ / 32);
    int y  = (bid / (W_ / 32)) % H_;
    int vb = bid / ((W_ / 32) * H_);
    int x0 = xt * 32;
    int tid = threadIdx.x;
    int xl = tid & 31;
    int ch = tid >> 5;   // 0..7
#pragma unroll
    for (int it = 0; it < 4; it++) {
        int c = it * 8 + ch;
        lds[c][xl] = feat[((size_t)(vb * C_ + c) * H_ + y) * W_ + x0 + xl];
    }
    __syncthreads();
    int c4 = tid & 7;
    int xw = tid >> 3;   // 0..31
    float4 o;
    o.x = lds[c4*4+0][xw];
    o.y = lds[c4*4+1][xw];
    o.z = lds[c4*4+2][xw];
    o.w = lds[c4*4+3][xw];
    *(float4*)(featT + ((size_t)(vb * H_ + y) * W_ + x0 + xw) * C_ + c4 * 4) = o;
}

// cost (B,D,H,W): each 8-lane group owns (pixel, 8 consecutive d).
// Lane c4 computes the projection for d0+c4 (d-parallel, no replication);
// j-loop broadcasts lane j's weights/offsets via shfl, all lanes gather
// their channel quarter, blend, dot, butterfly-reduce.
__global__ void __launch_bounds__(256) cost_kernel(const float* __restrict__ featT,
                                                   const float* __restrict__ depth,
                                                   const float* __restrict__ unc,
                                                   const float* __restrict__ proj,
                                                   float* __restrict__ cost) {
    int tid = threadIdx.x;
    int g  = tid >> 3;
    int c4 = tid & 7;
    int gid = blockIdx.x * 32 + g;
    int dt  = gid & 3;         // d-tile (8 d's each)
    int pix = gid >> 2;        // (b*H + y)*W + x
    int x = pix % W_;
    int y = (pix / W_) % H_;
    int b = pix / (W_ * H_);
    int d0 = dt * 8;

    int idx_d = ((b * D_ + d0 + c4) * H_ + y) * W_ + x;
    float dep = depth[idx_d];

    // per-lane projection for its own d (both views)
    float wgt[2][4];
    int   off[2][4];
    float fx = (float)x, fy = (float)y;
#pragma unroll
    for (int v = 0; v < 2; v++) {
        const float* P = proj + ((size_t)v * B_ + b) * 12;
        float rx = P[0]*fx + P[1]*fy + P[2];
        float ry = P[3]*fx + P[4]*fy + P[5];
        float rz = P[6]*fx + P[7]*fy + P[8];
        float px = rx * dep + P[9];
        float py = ry * dep + P[10];
        float pz = rz * dep + P[11];
        float t0 = px / pz;
        float t1 = py / pz;
        float gx = t0 / ((W_ - 1) * 0.5f) - 1.0f;
        float gy = t1 / ((H_ - 1) * 0.5f) - 1.0f;
        float ix = ((gx + 1.0f) * W_ - 1.0f) * 0.5f;
        float iy = ((gy + 1.0f) * H_ - 1.0f) * 0.5f;
        float x0f = floorf(ix), y0f = floorf(iy);
        float wx = ix - x0f, wy = iy - y0f;
        int x0 = (int)x0f, y0 = (int)y0f;
        int x1 = x0 + 1, y1 = y0 + 1;
        bool vx0 = (x0 >= 0) && (x0 <= W_ - 1);
        bool vx1 = (x1 >= 0) && (x1 <= W_ - 1);
        bool vy0 = (y0 >= 0) && (y0 <= H_ - 1);
        bool vy1 = (y1 >= 0) && (y1 <= H_ - 1);
        wgt[v][0] = (vx0 && vy0) ? (1.0f - wx) * (1.0f - wy) : 0.0f;
        wgt[v][1] = (vx1 && vy0) ? wx * (1.0f - wy) : 0.0f;
        wgt[v][2] = (vx0 && vy1) ? (1.0f - wx) * wy : 0.0f;
        wgt[v][3] = (vx1 && vy1) ? wx * wy : 0.0f;
        int xc0 = min(max(x0, 0), W_ - 1), xc1 = min(max(x1, 0), W_ - 1);
        int yc0 = min(max(y0, 0), H_ - 1), yc1 = min(max(y1, 0), H_ - 1);
        off[v][0] = yc0 * W_ + xc0;
        off[v][1] = yc0 * W_ + xc1;
        off[v][2] = yc1 * W_ + xc0;
        off[v][3] = yc1 * W_ + xc1;
    }

    const float4* fT4 = (const float4*)featT;
    const float4 ref4 = fT4[(size_t)pix * 8 + c4];
    int base1 = (1 * B_ + b) * HW_;   // view 1
    int base2 = (2 * B_ + b) * HW_;   // view 2

    float u = unc[pix];
    float sig = 1.0f / (1.0f + expf(-u));

    float myres = 0.0f;
#pragma unroll
    for (int j = 0; j < 8; j++) {
        float pv[2];
#pragma unroll
        for (int v = 0; v < 2; v++) {
            float W00 = __shfl(wgt[v][0], j, 8);
            float W01 = __shfl(wgt[v][1], j, 8);
            float W10 = __shfl(wgt[v][2], j, 8);
            float W11 = __shfl(wgt[v][3], j, 8);
            int O00 = __shfl(off[v][0], j, 8);
            int O01 = __shfl(off[v][1], j, 8);
            int O10 = __shfl(off[v][2], j, 8);
            int O11 = __shfl(off[v][3], j, 8);
            int base = v ? base2 : base1;
            float4 a  = fT4[(size_t)(base + O00) * 8 + c4];
            float4 bq = fT4[(size_t)(base + O01) * 8 + c4];
            float4 cq = fT4[(size_t)(base + O10) * 8 + c4];
            float4 dq = fT4[(size_t)(base + O11) * 8 + c4];
            float sx = W00*a.x + W01*bq.x + W10*cq.x + W11*dq.x;
            float sy = W00*a.y + W01*bq.y + W10*cq.y + W11*dq.y;
            float sz = W00*a.z + W01*bq.z + W10*cq.z + W11*dq.z;
            float sw = W00*a.w + W01*bq.w + W10*cq.w + W11*dq.w;
            float p = ref4.x*sx + ref4.y*sy + ref4.z*sz + ref4.w*sw;
            p += __shfl_xor(p, 1);
            p += __shfl_xor(p, 2);
            p += __shfl_xor(p, 4);
            pv[v] = p;
        }
        float r = fminf(pv[0], pv[1]) * sig;
        if (c4 == j) myres = r;
    }
    cost[idx_d] = myres;
}

// w_feat: 8 lanes per pixel; softmax over 25 neighbor dots; stored (25, B*H*W)
__global__ void __launch_bounds__(256) wfeat_kernel(const float* __restrict__ featT,
                                                    float* __restrict__ wfeat) {
    int tid = threadIdx.x;
    int g  = tid >> 3;
    int c4 = tid & 7;
    int pix = blockIdx.x * 32 + g;
    int x = pix % W_;
    int y = (pix / W_) % H_;
    int b = pix / (W_ * H_);
    const float4 r = *(const float4*)(featT + (size_t)pix * C_ + c4 * 4);
    float logit[25];
#pragma unroll
    for (int k = 0; k < 25; k++) {
        int dy = k / 5 - 2, dx = k % 5 - 2;
        int ny = y + dy, nx = x + dx;
        float p = 0.0f;
        if (ny >= 0 && ny < H_ && nx >= 0 && nx < W_) {
            const float4 q = *(const float4*)(featT + ((size_t)(b * H_ + ny) * W_ + nx) * C_ + c4 * 4);
            p = r.x*q.x + r.y*q.y + r.z*q.z + r.w*q.w;
        }
        p += __shfl_xor(p, 1);
        p += __shfl_xor(p, 2);
        p += __shfl_xor(p, 4);
        logit[k] = p;
    }
    float m = logit[0];
#pragma unroll
    for (int k = 1; k < 25; k++) m = fmaxf(m, logit[k]);
    float s = 0.0f;
#pragma unroll
    for (int k = 0; k < 25; k++) { logit[k] = expf(logit[k] - m); s += logit[k]; }
    float inv_s = 1.0f / s;
#pragma unroll
    for (int t = 0; t < 3; t++) {
        int k = c4 + 8 * t;
        wfeat[(size_t)k * NPIX_ + pix] = logit[k] * inv_s;
    }
    if (c4 == 0) wfeat[(size_t)24 * NPIX_ + pix] = logit[24] * inv_s;
}

// agg (B,D,H,W)
__global__ void __launch_bounds__(256) agg_kernel(const float* __restrict__ depth,
                                                  const float* __restrict__ cost,
                                                  const float* __restrict__ wfeat,
                                                  float* __restrict__ agg) {
    int idx = blockIdx.x * 256 + threadIdx.x;
    if (idx >= NCOST_) return;
    int x = idx % W_;
    int y = (idx / W_) % H_;
    int d = (idx / (W_ * H_)) % D_;
    int b = idx / (W_ * H_ * D_);
    float dc = depth[idx];
    size_t dslice = ((size_t)b * D_ + d) * HW_;
    int pix = (b * H_ + y) * W_ + x;

    float wd[25];
    float m1 = -1e30f;
#pragma unroll
    for (int k = 0; k < 25; k++) {
        int dy = k / 5 - 2, dx = k % 5 - 2;
        int ny = y + dy, nx = x + dx;
        bool ok = (ny >= 0 && ny < H_ && nx >= 0 && nx < W_);
        float nd = ok ? depth[dslice + ny * W_ + nx] : 0.0f;
        float l = -fabsf(nd - dc);
        wd[k] = l;
        m1 = fmaxf(m1, l);
    }
    float s1 = 0.0f;
#pragma unroll
    for (int k = 0; k < 25; k++) { wd[k] = expf(wd[k] - m1); s1 += wd[k]; }
    float inv_s1 = 1.0f / s1;

    float lg[25];
    float m2 = -1e30f;
#pragma unroll
    for (int k = 0; k < 25; k++) {
        float wf = wfeat[(size_t)k * NPIX_ + pix];
        float l = (wd[k] * inv_s1) * wf;
        lg[k] = l;
        m2 = fmaxf(m2, l);
    }
    float s2 = 0.0f;
    float acc = 0.0f;
#pragma unroll
    for (int k = 0; k < 25; k++) {
        float e = expf(lg[k] - m2);
        s2 += e;
        int dy = k / 5 - 2, dx = k % 5 - 2;
        int ny = y + dy, nx = x + dx;
        bool ok = (ny >= 0 && ny < H_ && nx >= 0 && nx < W_);
        float cv = ok ? cost[dslice + ny * W_ + nx] : 0.0f;
        acc += cv * e;
    }
    agg[idx] = acc / s2;
}

// softmax over D + expectation -> out (B,H,W)
__global__ void __launch_bounds__(256) final_kernel(const float* __restrict__ agg,
                                                    const float* __restrict__ depth,
                                                    float* __restrict__ out) {
    int idx = blockIdx.x * 256 + threadIdx.x;
    if (idx >= NPIX_) return;
    int x = idx % W_;
    int y = (idx / W_) % H_;
    int b = idx / (W_ * H_);
    float a[D_];
    float m = -1e30f;
#pragma unroll
    for (int d = 0; d < D_; d++) {
        a[d] = agg[((size_t)(b * D_ + d) * H_ + y) * W_ + x];
        m = fmaxf(m, a[d]);
    }
    float s = 0.0f, ws = 0.0f;
#pragma unroll
    for (int d = 0; d < D_; d++) {
        float e = expf(a[d] - m);
        s += e;
        ws += e * depth[((size_t)(b * D_ + d) * H_ + y) * W_ + x];
    }
    out[idx] = ws / s;
}

extern "C" void kernel_launch(void* const* d_in, const int* in_sizes, int n_in,
                              void* d_out, int out_size, void* d_ws, size_t ws_size,
                              hipStream_t stream) {
    const float* features = (const float*)d_in[0];  // (3,2,32,128,160)
    const float* intr     = (const float*)d_in[1];  // (3,2,3,3)
    const float* c2w      = (const float*)d_in[2];  // (3,2,4,4)
    const float* depth    = (const float*)d_in[3];  // (2,32,128,160)
    const float* unc      = (const float*)d_in[4];  // (2,128,160)
    float* out = (float*)d_out;

    float* ws    = (float*)d_ws;
    float* featT = ws;                          // NFEATT_
    float* cost  = featT + NFEATT_;             // NCOST_
    float* wfeat = cost + NCOST_;               // 25*NPIX_
    float* agg   = wfeat + (size_t)25 * NPIX_;  // NCOST_
    float* proj  = agg + NCOST_;                // 48

    hipLaunchKernelGGL(proj_kernel, dim3(1), dim3(64), 0, stream, intr, c2w, proj);
    hipLaunchKernelGGL(transpose_kernel, dim3(V_ * B_ * H_ * (W_ / 32)), dim3(256), 0, stream, features, featT);
    hipLaunchKernelGGL(cost_kernel, dim3((NPIX_ * 4) / 32), dim3(256), 0, stream, featT, depth, unc, proj, cost);
    hipLaunchKernelGGL(wfeat_kernel, dim3(NPIX_ / 32), dim3(256), 0, stream, featT, wfeat);
    hipLaunchKernelGGL(agg_kernel, dim3(NCOST_ / 256), dim3(256), 0, stream, depth, cost, wfeat, agg);
    hipLaunchKernelGGL(final_kernel, dim3(NPIX_ / 256), dim3(256), 0, stream, agg, depth, out);
}